// Round 5
// baseline (1361.846 us; speedup 1.0000x reference)
//
#include <hip/hip_runtime.h>
#include <hip/hip_bf16.h>
#include <math.h>

#define BATCH 8192
#define DDIM 256
#define HDIM 266
#define NPAD 320
#define TSTEPS 20
#define BN_EPS 1e-5f
#define LSTR 72         // LDS row stride in shorts (144 B)
#define NBLK 256
#define NTH 512
#define NCPY 8          // stats contention split (8-way)
#define NBARCNT 16      // barrier sub-counters per slot
#define NBAR 64         // barrier slots

typedef __attribute__((ext_vector_type(8))) short short8;   // 8 bf16
typedef __attribute__((ext_vector_type(4))) float f32x4;

__device__ __forceinline__ short f2bf(float f) {
    __hip_bfloat16 h = __float2bfloat16(f);
    return *reinterpret_cast<short*>(&h);
}
__device__ __forceinline__ float bf2f(short s) {
    union { unsigned u; float f; } v;
    v.u = ((unsigned)(unsigned short)s) << 16;
    return v.f;
}

// ---------------------------------------------------------------------------
// prep: pad+convert all weights (bf16) / biases (fp32); zero stats + barriers.
// ---------------------------------------------------------------------------
#define SZ_W1B (20L * 320 * 256)
#define SZ_W2B (20L * 320 * 320)
#define SZ_W3B (20L * 256 * 320)
#define SZ_VW1 (320L * 256)
#define SZ_VW2 (320L * 320)
#define SZ_B1P (20L * 320)
#define SZ_B2P (20L * 320)
#define ZCOUNT (4L * 21 * NCPY * NPAD + 2 * NCPY + NBAR * NBARCNT)
#define PREP_TOTAL (SZ_W1B + SZ_W2B + SZ_W3B + SZ_VW1 + SZ_VW2 + SZ_B1P + SZ_B2P + 3 * 320 + ZCOUNT)

__global__ __launch_bounds__(256)
void prep_k(short* __restrict__ W1b, const float* __restrict__ W1,
            short* __restrict__ W2b, const float* __restrict__ W2,
            short* __restrict__ W3b, const float* __restrict__ W3,
            short* __restrict__ vW1b, const float* __restrict__ vW1,
            short* __restrict__ vW2b, const float* __restrict__ vW2,
            float* __restrict__ b1p, const float* __restrict__ b1,
            float* __restrict__ b2p, const float* __restrict__ b2,
            float* __restrict__ vb1p, const float* __restrict__ vb1,
            float* __restrict__ vb2p, const float* __restrict__ vb2,
            float* __restrict__ vW3p, const float* __restrict__ vW3,
            float* __restrict__ zbase)
{
    long idx = (long)blockIdx.x * 256 + threadIdx.x;
    if (idx < SZ_W1B) {  // [20][320][256], src [20][266][256]
        long k = idx % 256, r = (idx / 256) % 320, t = idx / (256L * 320);
        float v = (r < HDIM) ? W1[((size_t)t * HDIM + r) * 256 + k] : 0.0f;
        W1b[idx] = f2bf(v); return;
    }
    idx -= SZ_W1B;
    if (idx < SZ_W2B) {  // [20][320][320], src [20][266][266]
        long k = idx % 320, r = (idx / 320) % 320, t = idx / (320L * 320);
        float v = (r < HDIM && k < HDIM) ? W2[((size_t)t * HDIM + r) * HDIM + k] : 0.0f;
        W2b[idx] = f2bf(v); return;
    }
    idx -= SZ_W2B;
    if (idx < SZ_W3B) {  // [20][256][320], src [20][256][266]
        long k = idx % 320, r = (idx / 320) % 256, t = idx / (320L * 256);
        float v = (k < HDIM) ? W3[((size_t)t * 256 + r) * HDIM + k] : 0.0f;
        W3b[idx] = f2bf(v); return;
    }
    idx -= SZ_W3B;
    if (idx < SZ_VW1) {  // [320][256], src [266][256]
        long k = idx % 256, r = idx / 256;
        float v = (r < HDIM) ? vW1[(size_t)r * 256 + k] : 0.0f;
        vW1b[idx] = f2bf(v); return;
    }
    idx -= SZ_VW1;
    if (idx < SZ_VW2) {  // [320][320], src [266][266]
        long k = idx % 320, r = idx / 320;
        float v = (r < HDIM && k < HDIM) ? vW2[(size_t)r * HDIM + k] : 0.0f;
        vW2b[idx] = f2bf(v); return;
    }
    idx -= SZ_VW2;
    if (idx < SZ_B1P) { long n = idx % 320, t = idx / 320;
        b1p[idx] = (n < HDIM) ? b1[(size_t)t * HDIM + n] : 0.0f; return; }
    idx -= SZ_B1P;
    if (idx < SZ_B2P) { long n = idx % 320, t = idx / 320;
        b2p[idx] = (n < HDIM) ? b2[(size_t)t * HDIM + n] : 0.0f; return; }
    idx -= SZ_B2P;
    if (idx < 320) { vb1p[idx] = (idx < HDIM) ? vb1[idx] : 0.0f; return; }
    idx -= 320;
    if (idx < 320) { vb2p[idx] = (idx < HDIM) ? vb2[idx] : 0.0f; return; }
    idx -= 320;
    if (idx < 320) { vW3p[idx] = (idx < HDIM) ? vW3[idx] : 0.0f; return; }
    idx -= 320;
    if (idx < ZCOUNT) { zbase[idx] = 0.0f; return; }
}

// ---------------------------------------------------------------------------
// Light grid barrier (round-3-proven concept, distributed arrival):
// 16 sub-counters per slot; arrival = one atomicAdd by tid0 to sub-counter
// (bid&15). Wave 0 spins: every lane loads sub-counter (lane&15) — lanes
// 16..63 mirror lanes 0..15 — and the wave exits when __all counters hit
// NBLK/16. Cross-block data travels only via device-scope atomics, so no
// L2 flush is needed (unlike cg::grid_group::sync, ~30 µs).
// ---------------------------------------------------------------------------
__device__ __forceinline__ void gridbar(unsigned* __restrict__ bar, int idx,
                                        int tid, int bid)
{
    asm volatile("s_waitcnt vmcnt(0) lgkmcnt(0)" ::: "memory");
    __syncthreads();
    if (tid == 0)
        __hip_atomic_fetch_add(&bar[idx * NBARCNT + (bid & (NBARCNT - 1))], 1u,
                               __ATOMIC_RELAXED, __HIP_MEMORY_SCOPE_AGENT);
    if (tid < 64) {
        const unsigned* c = &bar[idx * NBARCNT + (tid & (NBARCNT - 1))];
        for (;;) {
            unsigned v = __hip_atomic_load(c, __ATOMIC_RELAXED,
                                           __HIP_MEMORY_SCOPE_AGENT);
            if (__all(v >= (unsigned)(NBLK / NBARCNT))) break;
            __builtin_amdgcn_s_sleep(1);
        }
    }
    __syncthreads();
}

__device__ __forceinline__ float aload(const float* p)
{
    return __hip_atomic_load(p, __ATOMIC_RELAXED, __HIP_MEMORY_SCOPE_AGENT);
}

// BN coeffs: sum the NCPY stat copies with coherent loads.
__device__ __forceinline__ void bn_coeff8(const float* __restrict__ cs,
                                          const float* __restrict__ cq,
                                          const float* __restrict__ g,
                                          const float* __restrict__ be,
                                          float* sS, float* sT, int tid)
{
    for (int k = tid; k < NPAD; k += NTH) {
        float s = 0.0f, t = 0.0f;
        if (k < HDIM) {
            float a = 0.0f, b = 0.0f;
            #pragma unroll
            for (int c = 0; c < NCPY; ++c) {
                a += aload(&cs[c * NPAD + k]);
                b += aload(&cq[c * NPAD + k]);
            }
            float mn = a * (1.0f / BATCH);
            float vr = b * (1.0f / BATCH) - mn * mn;
            float rs = rsqrtf(fmaxf(vr, 0.0f) + BN_EPS);
            s = g[k] * rs;
            t = be[k] - mn * s;
        }
        sS[k] = s; sT[k] = t;
    }
}

// ---------------------------------------------------------------------------
// B-direct GEMM: out 32 x (4*NJ*16), K = KS*32. A from chunk-major LDS
// ([c64][32][LSTR]); if BN, the whole A is re-normalized into As1 first (one
// sync), then A-fragments live in registers. B-fragments load straight from
// global (L2-resident weights) — no LDS staging, no per-chunk syncs.
// Wave w: row-half rh=w>>2 (16 rows), col-quarter ch=w&3 (NJ tiles).
// ---------------------------------------------------------------------------
template<int KS, int NJ, bool BN>
__device__ __forceinline__ void gemm_direct(
    const short* __restrict__ W, const short* Abuf, short* As1,
    const float* sS, const float* sT, f32x4* acc, int tid)
{
    const int lane = tid & 63, q = lane >> 4, m = lane & 15;
    const int w = tid >> 6, rh = w >> 2, ch = w & 3;

    if (BN) {
        const int NG = KS * 4;               // short8 groups per row
        for (int f = tid; f < 32 * NG; f += NTH) {
            int kg = f % NG, row = f / NG;
            int k = kg * 8;
            int adr = ((k >> 6) * 32 + row) * LSTR + (k & 63);
            short8 v = *(const short8*)&Abuf[adr];
            short8 ta;
            #pragma unroll
            for (int j = 0; j < 8; ++j) {
                float fx = bf2f(v[j]);
                fx = fmaxf(fx * sS[k + j] + sT[k + j], 0.0f);
                ta[j] = f2bf(fx);
            }
            *(short8*)&As1[adr] = ta;
        }
        __syncthreads();
    }
    const short* AB = BN ? As1 : Abuf;

    short8 af[KS];
    #pragma unroll
    for (int s = 0; s < KS; ++s)
        af[s] = *(const short8*)&AB[((s >> 1) * 32 + rh * 16 + m) * LSTR
                                    + (s & 1) * 32 + q * 8];
    #pragma unroll
    for (int j = 0; j < NJ; ++j) acc[j] = (f32x4){0.f, 0.f, 0.f, 0.f};

    const int KLEN = KS * 32;
    const short* wb = W + (size_t)(ch * (NJ * 16) + m) * KLEN + q * 8;
    #pragma unroll
    for (int s = 0; s < KS; ++s) {
        short8 b[NJ];
        #pragma unroll
        for (int j = 0; j < NJ; ++j)
            b[j] = *(const short8*)(wb + (size_t)j * 16 * KLEN + s * 32);
        #pragma unroll
        for (int j = 0; j < NJ; ++j)
            acc[j] = __builtin_amdgcn_mfma_f32_16x16x32_bf16(af[s], b[j], acc[j], 0, 0, 0);
    }
}

// Epilogue for 320-wide phases: bias, store pre-BN h to chunk-major LDS,
// column sum/sq -> split atomics straight from registers (no LDS pass).
__device__ __forceinline__ void epi320(const f32x4* acc, const float* __restrict__ bias,
                                       short* dst, float* __restrict__ cs,
                                       float* __restrict__ cq, int tid, int bid)
{
    const int lane = tid & 63, q = lane >> 4, m = lane & 15;
    const int w = tid >> 6, rh = w >> 2, ch = w & 3;
    #pragma unroll
    for (int j = 0; j < 5; ++j) {
        const int col = ch * 80 + j * 16 + m;
        const float bv = bias[col];
        float s = 0.0f, sq = 0.0f;
        #pragma unroll
        for (int r = 0; r < 4; ++r) {
            float v = acc[j][r] + bv;
            int row = rh * 16 + q * 4 + r;
            dst[((col >> 6) * 32 + row) * LSTR + (col & 63)] = f2bf(v);
            s += v; sq += v * v;
        }
        s  += __shfl_xor(s, 16);  s  += __shfl_xor(s, 32);
        sq += __shfl_xor(sq, 16); sq += __shfl_xor(sq, 32);
        if (q == 0 && col < HDIM) {
            atomicAdd(&cs[(bid & (NCPY - 1)) * NPAD + col], s);
            atomicAdd(&cq[(bid & (NCPY - 1)) * NPAD + col], sq);
        }
    }
}

struct PArgs {
    const float* x; const float* xi; const float* tg;
    const short* W1b; const short* W2b; const short* W3b;
    const short* vW1b; const short* vW2b;
    const float* b1p; const float* b2p; const float* b3;
    const float* vb1p; const float* vb2p; const float* vW3p; const float* vb3;
    const float* g1; const float* be1; const float* g2; const float* be2;
    const float* vg1; const float* vbe1; const float* vg2; const float* vbe2;
    const float* vg3; const float* vbe3;
    float* csA; float* cqA; float* csB; float* cqB;
    float* s3; float* q3;
    unsigned* bars;
    float* out; float* xout;
};

// ---------------------------------------------------------------------------
// Persistent kernel: 256 blocks x 512 threads (8 waves, 2x4), 32 rows/block.
// xt/h1/h2 in LDS for the whole scan; B-direct GEMMs; light barriers.
// ---------------------------------------------------------------------------
__global__ __launch_bounds__(NTH)
void persist_k(PArgs p)
{
    __shared__ __align__(16) short xbuf[4 * 32 * LSTR];    // xt  [4][32][LSTR]
    __shared__ __align__(16) short h1buf[5 * 32 * LSTR];   // h1  pre-BN
    __shared__ __align__(16) short h2buf[5 * 32 * LSTR];   // h2  pre-BN
    __shared__ __align__(16) short As1[5 * 32 * LSTR];     // BN-staged A
    __shared__ float sS[NPAD], sT[NPAD];
    __shared__ float redF[128], redD[128];
    __shared__ float pre3L[32], vacc[32];

    const int tid = threadIdx.x;
    const int bid = blockIdx.x;
    const int row0 = bid * 32;
    const int lane = tid & 63, w = tid >> 6, q = lane >> 4, m = lane & 15;
    const int rh = w >> 2, ch = w & 3;
    int bidx = 0;

    // stage x -> xbuf (bf16, chunk-major)
    for (int i2 = tid; i2 < 32 * 256; i2 += NTH) {
        int row = i2 >> 8, col = i2 & 255;
        xbuf[((col >> 6) * 32 + row) * LSTR + (col & 63)] =
            f2bf(p.x[(size_t)(row0 + row) * DDIM + col]);
    }
    if (tid < 32) vacc[tid] = 0.0f;
    __syncthreads();

    f32x4 acc[5];

    // ---- v-net layer 1 ----
    gemm_direct<8, 5, false>(p.vW1b, xbuf, As1, sS, sT, acc, tid);
    epi320(acc, p.vb1p, h1buf, p.csA + 20L * NCPY * NPAD, p.cqA + 20L * NCPY * NPAD,
           tid, bid);
    gridbar(p.bars, bidx++, tid, bid);

    // ---- v-net layer 2 ----
    bn_coeff8(p.csA + 20L * NCPY * NPAD, p.cqA + 20L * NCPY * NPAD,
              p.vg1, p.vbe1, sS, sT, tid);
    __syncthreads();
    gemm_direct<10, 5, true>(p.vW2b, h1buf, As1, sS, sT, acc, tid);
    epi320(acc, p.vb2p, h2buf, p.csB + 20L * NCPY * NPAD, p.cqB + 20L * NCPY * NPAD,
           tid, bid);
    gridbar(p.bars, bidx++, tid, bid);

    // ---- v-net layer 3: row dot (block-local) ----
    bn_coeff8(p.csB + 20L * NCPY * NPAD, p.cqB + 20L * NCPY * NPAD,
              p.vg2, p.vbe2, sS, sT, tid);
    __syncthreads();
    {
        const int wv = tid >> 6, ln = tid & 63;
        float ps = 0.0f, pq = 0.0f;
        #pragma unroll
        for (int r4 = 0; r4 < 4; ++r4) {
            int row = wv * 4 + r4;
            float sum = 0.0f;
            #pragma unroll
            for (int c = 0; c < 5; ++c) {
                int k = c * 64 + ln;
                float v = fmaxf(bf2f(h2buf[(c * 32 + row) * LSTR + ln]) * sS[k] + sT[k],
                                0.0f);
                sum += v * p.vW3p[k];
            }
            sum += __shfl_xor(sum, 1);  sum += __shfl_xor(sum, 2);
            sum += __shfl_xor(sum, 4);  sum += __shfl_xor(sum, 8);
            sum += __shfl_xor(sum, 16); sum += __shfl_xor(sum, 32);
            if (ln == 0) {
                float pv = sum + p.vb3[0];
                pre3L[row] = pv;
                ps += pv; pq += pv * pv;
            }
        }
        if (ln == 0) { redF[wv] = ps; redD[wv] = pq; }
        __syncthreads();
        if (tid == 0) {
            float a = 0.0f, b = 0.0f;
            #pragma unroll
            for (int i = 0; i < 8; ++i) { a += redF[i]; b += redD[i]; }
            atomicAdd(&p.s3[bid & (NCPY - 1)], a);
            atomicAdd(&p.q3[bid & (NCPY - 1)], b);
        }
    }

    // ---- scan: 20 steps, 2 barriers each ----
    for (int t = 0; t < TSTEPS; ++t) {
        // L1: h1 = xt @ W1t^T  (xt block-local; no staging sync needed)
        gemm_direct<8, 5, false>(p.W1b + (size_t)t * NPAD * DDIM, xbuf, As1,
                                 sS, sT, acc, tid);
        epi320(acc, p.b1p + t * NPAD, h1buf,
               p.csA + (size_t)t * NCPY * NPAD, p.cqA + (size_t)t * NCPY * NPAD,
               tid, bid);
        gridbar(p.bars, bidx++, tid, bid);

        // L2: h2 = bnrelu(h1) @ W2t^T
        bn_coeff8(p.csA + (size_t)t * NCPY * NPAD, p.cqA + (size_t)t * NCPY * NPAD,
                  p.g1 + (size_t)t * HDIM, p.be1 + (size_t)t * HDIM, sS, sT, tid);
        __syncthreads();
        gemm_direct<10, 5, true>(p.W2b + (size_t)t * NPAD * NPAD, h1buf, As1,
                                 sS, sT, acc, tid);
        epi320(acc, p.b2p + t * NPAD, h2buf,
               p.csB + (size_t)t * NCPY * NPAD, p.cqB + (size_t)t * NCPY * NPAD,
               tid, bid);
        gridbar(p.bars, bidx++, tid, bid);

        // L3: grad = bnrelu(h2) @ W3t^T + SDE update (block-local)
        const float* xi_t = p.xi + (size_t)t * BATCH * DDIM;
        float xiv[16];
        #pragma unroll
        for (int j = 0; j < 4; ++j)
            #pragma unroll
            for (int r = 0; r < 4; ++r)
                xiv[j * 4 + r] = xi_t[(size_t)(row0 + rh * 16 + q * 4 + r) * DDIM
                                      + ch * 64 + j * 16 + m];

        bn_coeff8(p.csB + (size_t)t * NCPY * NPAD, p.cqB + (size_t)t * NCPY * NPAD,
                  p.g2 + (size_t)t * HDIM, p.be2 + (size_t)t * HDIM, sS, sT, tid);
        __syncthreads();
        gemm_direct<10, 4, true>(p.W3b + (size_t)t * DDIM * NPAD, h2buf, As1,
                                 sS, sT, acc, tid);

        const float ht = p.tg[t + 1] - p.tg[t];
        const float sn = sqrtf(ht);
        float fr[4] = {0.f, 0.f, 0.f, 0.f};
        float dr[4] = {0.f, 0.f, 0.f, 0.f};
        #pragma unroll
        for (int j = 0; j < 4; ++j) {
            const int col = ch * 64 + j * 16 + m;
            const float bv = p.b3[(size_t)t * DDIM + col];
            #pragma unroll
            for (int r = 0; r < 4; ++r) {
                const int row = rh * 16 + q * 4 + r;
                float grad = acc[j][r] + bv;
                float noise = sn * xiv[j * 4 + r];
                const int xo = (ch * 32 + row) * LSTR + (j * 16 + m);
                float nx = bf2f(xbuf[xo]) - grad * ht + noise;
                xbuf[xo] = f2bf(nx);
                if (t == TSTEPS - 1)
                    p.xout[(size_t)(row0 + row) * DDIM + col] = nx;
                fr[r] += grad * grad;
                dr[r] += grad * noise;
            }
        }
        #pragma unroll
        for (int r = 0; r < 4; ++r) {
            fr[r] += __shfl_xor(fr[r], 1); dr[r] += __shfl_xor(dr[r], 1);
            fr[r] += __shfl_xor(fr[r], 2); dr[r] += __shfl_xor(dr[r], 2);
            fr[r] += __shfl_xor(fr[r], 4); dr[r] += __shfl_xor(dr[r], 4);
            fr[r] += __shfl_xor(fr[r], 8); dr[r] += __shfl_xor(dr[r], 8);
        }
        if (m == 0) {
            #pragma unroll
            for (int r = 0; r < 4; ++r) {
                redF[ch * 32 + rh * 16 + q * 4 + r] = fr[r];
                redD[ch * 32 + rh * 16 + q * 4 + r] = dr[r];
            }
        }
        __syncthreads();
        if (tid < 32) {
            float fsum = redF[tid] + redF[32 + tid] + redF[64 + tid] + redF[96 + tid];
            float dsum = redD[tid] + redD[32 + tid] + redD[64 + tid] + redD[96 + tid];
            vacc[tid] += dsum - fsum * ht;
        }
        __syncthreads();
    }

    // ---- final vT (s3/q3 complete ~40 barriers ago) ----
    if (tid < 32) {
        float a = 0.0f, b = 0.0f;
        #pragma unroll
        for (int c = 0; c < NCPY; ++c) { a += aload(&p.s3[c]); b += aload(&p.q3[c]); }
        float mn = a * (1.0f / BATCH);
        float va = fmaxf(b * (1.0f / BATCH) - mn * mn, 0.0f);
        float rs = rsqrtf(va + BN_EPS);
        float v0 = fmaxf(p.vg3[0] * (pre3L[tid] - mn) * rs + p.vbe3[0], 0.0f);
        p.out[row0 + tid] = v0 + vacc[tid];
    }
}

extern "C" void kernel_launch(void* const* d_in, const int* in_sizes, int n_in,
                              void* d_out, int out_size, void* d_ws, size_t ws_size,
                              hipStream_t stream)
{
    const float* x    = (const float*)d_in[0];
    const float* xi   = (const float*)d_in[1];
    const float* tg   = (const float*)d_in[2];
    const float* W1   = (const float*)d_in[3];
    const float* b1   = (const float*)d_in[4];
    const float* g1   = (const float*)d_in[5];
    const float* be1  = (const float*)d_in[6];
    const float* W2   = (const float*)d_in[7];
    const float* b2   = (const float*)d_in[8];
    const float* g2   = (const float*)d_in[9];
    const float* be2  = (const float*)d_in[10];
    const float* W3   = (const float*)d_in[11];
    const float* b3   = (const float*)d_in[12];
    const float* vW1  = (const float*)d_in[13];
    const float* vb1  = (const float*)d_in[14];
    const float* vg1  = (const float*)d_in[15];
    const float* vbe1 = (const float*)d_in[16];
    const float* vW2  = (const float*)d_in[17];
    const float* vb2  = (const float*)d_in[18];
    const float* vg2  = (const float*)d_in[19];
    const float* vbe2 = (const float*)d_in[20];
    const float* vW3  = (const float*)d_in[21];
    const float* vb3  = (const float*)d_in[22];
    const float* vg3  = (const float*)d_in[23];
    const float* vbe3 = (const float*)d_in[24];

    float* out  = (float*)d_out;       // [0,B): vT ; [B, B+B*D): xT (fp32)
    float* xout = out + BATCH;

    // ---- workspace layout: weights (bf16), then fp32 biases + stats ----
    short* W1b  = (short*)d_ws;
    short* W2b  = W1b + SZ_W1B;
    short* W3b  = W2b + SZ_W2B;
    short* vW1b = W3b + SZ_W3B;
    short* vW2b = vW1b + SZ_VW1;
    float* b1p  = (float*)(vW2b + SZ_VW2);
    float* b2p  = b1p + TSTEPS * NPAD;
    float* vb1p = b2p + TSTEPS * NPAD;
    float* vb2p = vb1p + NPAD;
    float* vW3p = vb2p + NPAD;
    float* csA  = vW3p + NPAD;                 // zero region starts here
    float* cqA  = csA + 21L * NCPY * NPAD;
    float* csB  = cqA + 21L * NCPY * NPAD;
    float* cqB  = csB + 21L * NCPY * NPAD;
    float* s3   = cqB + 21L * NCPY * NPAD;     // [NCPY]
    float* q3   = s3 + NCPY;                   // [NCPY]
    unsigned* bars = (unsigned*)(q3 + NCPY);   // NBAR*NBARCNT, zeroed by prep

    prep_k<<<dim3((int)((PREP_TOTAL + 255) / 256)), dim3(256), 0, stream>>>(
        W1b, W1, W2b, W2, W3b, W3, vW1b, vW1, vW2b, vW2,
        b1p, b1, b2p, b2, vb1p, vb1, vb2p, vb2, vW3p, vW3, csA);

    PArgs pa;
    pa.x = x; pa.xi = xi; pa.tg = tg;
    pa.W1b = W1b; pa.W2b = W2b; pa.W3b = W3b;
    pa.vW1b = vW1b; pa.vW2b = vW2b;
    pa.b1p = b1p; pa.b2p = b2p; pa.b3 = b3;
    pa.vb1p = vb1p; pa.vb2p = vb2p; pa.vW3p = vW3p; pa.vb3 = vb3;
    pa.g1 = g1; pa.be1 = be1; pa.g2 = g2; pa.be2 = be2;
    pa.vg1 = vg1; pa.vbe1 = vbe1; pa.vg2 = vg2; pa.vbe2 = vbe2;
    pa.vg3 = vg3; pa.vbe3 = vbe3;
    pa.csA = csA; pa.cqA = cqA; pa.csB = csB; pa.cqB = cqB;
    pa.s3 = s3; pa.q3 = q3;
    pa.bars = bars;
    pa.out = out; pa.xout = xout;

    void* kargs[] = { (void*)&pa };
    hipLaunchCooperativeKernel((const void*)persist_k, dim3(NBLK), dim3(NTH),
                               kargs, 0, stream);
}